// Round 3
// baseline (2899.936 us; speedup 1.0000x reference)
//
#include <hip/hip_runtime.h>
#include <hip/hip_cooperative_groups.h>
#include <math.h>
#include <stdint.h>

namespace cg = cooperative_groups;

#define Bz 64
#define Tz 32
#define Ez 64
#define Hz 256
#define Vz 32000
#define KTOT 320
#define KPAD 324     // pLDS gate stride (banks 0/4/8/12 -> conflict-free)
#define XPAD 68      // xLDS row stride (breaks 16-way bank conflict)
#define NBLK 256
#define LBLK 250     // blocks holding a Wo slice
#define CPB 128      // Wo cols per block

typedef unsigned long long u64;
typedef unsigned int u32;

__device__ __forceinline__ u32 map_f32(float f) {
  u32 u = __float_as_uint(f);
  return (u & 0x80000000u) ? ~u : (u | 0x80000000u);
}

// LDS floats: wLDS 32768 | pLDS 4*324=1296 | xLDS 64*68=4352 | tok 64  => 38480 f = 153920 B
#define LDS_FLOATS (32768 + 4*KPAD + Bz*XPAD + 64)

__global__ void __launch_bounds__(1024, 1)
k_rollout(const int* __restrict__ input_x, const int* __restrict__ gnp,
          const int* __restrict__ start_tok, const float* __restrict__ emb,
          const float* __restrict__ Wi, const float* __restrict__ Ui, const float* __restrict__ bi_,
          const float* __restrict__ Wf, const float* __restrict__ Uf, const float* __restrict__ bf_,
          const float* __restrict__ Wog, const float* __restrict__ Uog, const float* __restrict__ bog_,
          const float* __restrict__ Wc, const float* __restrict__ Uc, const float* __restrict__ bc_,
          const float* __restrict__ Wo, const float* __restrict__ bo,
          float* __restrict__ hA, float* __restrict__ hB, float* __restrict__ c_g,
          float* __restrict__ hT, u64* __restrict__ key, int* __restrict__ out)
{
  extern __shared__ float sm[];
  float* wLDS = sm;                       // [k][128]
  float* pLDS = sm + 32768;               // 4 gates x KPAD
  float* xLDS = sm + 32768 + 4*KPAD;      // 64 rows x XPAD
  int*   tok_s = (int*)(sm + 32768 + 4*KPAD + Bz*XPAD);

  cg::grid_group grid = cg::this_grid();
  const int tid = threadIdx.x;
  const int blk = blockIdx.x;
  const int j   = blk;                    // gate column owned by this block
  const int gn  = gnp[0];

  // ---- one-time: gate weights for column j (strided gather, once) ----
  for (int idx = tid; idx < 4*KTOT; idx += 1024) {
    int g = idx / KTOT, k = idx - g*KTOT;
    const float* W = (g==0) ? Wi : (g==1) ? Wf : (g==2) ? Wog : Wc;
    const float* U = (g==0) ? Ui : (g==1) ? Uf : (g==2) ? Uog : Uc;
    pLDS[g*KPAD + k] = (k < Ez) ? W[(size_t)k*Hz + j] : U[(size_t)(k-Ez)*Hz + j];
  }
  // ---- one-time: Wo slice -> LDS (coalesced) ----
  if (blk < LBLK) {
    const float* wsrc = Wo + (size_t)blk * CPB;
    for (int idx = tid; idx < Hz*CPB; idx += 1024) {
      int k = idx >> 7, cl = idx & (CPB-1);
      wLDS[idx] = wsrc[(size_t)k*Vz + cl];
    }
  }
  __syncthreads();

  const int b = tid >> 2, q = tid & 3;    // gates decomposition (tid < 256)

  for (int t = 0; t < Tz; ++t) {
    const float* h_in  = (t & 1) ? hA : hB;
    float*       h_out = (t & 1) ? hB : hA;
    u64*       key_cur  = key + (size_t)(t & 1)*Bz;
    const u64* key_prev = key + (size_t)((t+1) & 1)*Bz;

    // ---- token select for step t ----
    if (tid < 256 && q == 0) {
      int tk;
      if (t == 0)           tk = start_tok[b];
      else if (t - 1 < gn)  tk = input_x[b*Tz + (t-1)];
      else                  tk = (int)(~(u32)(key_prev[b] & 0xFFFFFFFFull));
      tok_s[b] = tk;
      if (blk == 0 && t > 0) out[b*Tz + (t-1)] = tk;
    }
    if (blk == 0 && t >= gn && tid >= 512 && tid < 512 + Bz) key_cur[tid - 512] = 0ull;
    __syncthreads();

    // ---- stage x = emb[tok] (1024 float4 loads) ----
    {
      const float4* emb4 = (const float4*)emb;
      int row = tid >> 4, e4 = tid & 15;
      float4 v = emb4[(size_t)tok_s[row]*16 + e4];
      float* dst = xLDS + row*XPAD + e4*4;
      dst[0]=v.x; dst[1]=v.y; dst[2]=v.z; dst[3]=v.w;
    }
    __syncthreads();

    // ---- gates: thread (b,q) computes gate q of (b, j) ----
    if (tid < 256) {
      const float* wrow = pLDS + q*KPAD;
      const float* xrow = xLDS + b*XPAD;
      float a = 0.f;
      #pragma unroll
      for (int k = 0; k < Ez; k += 4) {
        float4 xv = *(const float4*)(xrow + k);
        float4 wv = *(const float4*)(wrow + k);
        a = fmaf(xv.x, wv.x, a); a = fmaf(xv.y, wv.y, a);
        a = fmaf(xv.z, wv.z, a); a = fmaf(xv.w, wv.w, a);
      }
      if (t > 0) {
        const float* hrow = h_in + b*Hz;
        #pragma unroll 8
        for (int k = 0; k < Hz; k += 4) {
          float4 xv = *(const float4*)(hrow + k);
          float4 wv = *(const float4*)(wrow + Ez + k);
          a = fmaf(xv.x, wv.x, a); a = fmaf(xv.y, wv.y, a);
          a = fmaf(xv.z, wv.z, a); a = fmaf(xv.w, wv.w, a);
        }
      }
      a += (q==0) ? bi_[j] : (q==1) ? bf_[j] : (q==2) ? bog_[j] : bc_[j];

      int lane = tid & 63, base = lane & ~3;
      float ai = __shfl(a, base+0, 64);
      float af = __shfl(a, base+1, 64);
      float ao = __shfl(a, base+2, 64);
      float ac = __shfl(a, base+3, 64);
      float gi = 1.f/(1.f + expf(-ai));
      float gf = 1.f/(1.f + expf(-af));
      float go = 1.f/(1.f + expf(-ao));
      float gc = tanhf(ac);
      float cold = (t > 0) ? c_g[b*Hz + j] : 0.f;
      float cn = gf*cold + gi*gc;
      float hn = go * tanhf(cn);
      if (q == 0)      h_out[b*Hz + j] = hn;
      else if (q == 1) c_g[b*Hz + j]   = cn;
      else if (q == 2) hT[j*Bz + b]    = hn;
    }
    grid.sync();                          // h/hT/key-zero visible grid-wide

    if (t >= gn) {
      if (blk < LBLK) {
        int w = tid >> 6, lane = tid & 63;
        int c0 = blk*CPB + w*8;
        const float* wl = wLDS + w*8;
        float acc[8];
        #pragma unroll
        for (int i = 0; i < 8; ++i) acc[i] = bo[c0 + i];
        const float* hTp = hT + lane;
        #pragma unroll 4
        for (int k = 0; k < Hz; ++k) {
          float vh = hTp[k*Bz];
          float4 w0 = *(const float4*)(wl + k*CPB);
          float4 w1 = *(const float4*)(wl + k*CPB + 4);
          acc[0]=fmaf(w0.x,vh,acc[0]); acc[1]=fmaf(w0.y,vh,acc[1]);
          acc[2]=fmaf(w0.z,vh,acc[2]); acc[3]=fmaf(w0.w,vh,acc[3]);
          acc[4]=fmaf(w1.x,vh,acc[4]); acc[5]=fmaf(w1.y,vh,acc[5]);
          acc[6]=fmaf(w1.z,vh,acc[6]); acc[7]=fmaf(w1.w,vh,acc[7]);
        }
        float bv = acc[0]; int bc = c0;
        #pragma unroll
        for (int i = 1; i < 8; ++i)
          if (acc[i] > bv) { bv = acc[i]; bc = c0 + i; }
        u64 kv = ((u64)map_f32(bv) << 32) | (u32)(~(u32)bc);
        atomicMax(key_cur + lane, kv);
      }
      grid.sync();                        // key complete; hT reads done
    }
  }

  // ---- final token (t = T-1) ----
  if (blk == 0 && tid < Bz) {
    int tk;
    if (Tz - 1 < gn) tk = input_x[tid*Tz + Tz-1];
    else             tk = (int)(~(u32)(key[(size_t)((Tz-1)&1)*Bz + tid] & 0xFFFFFFFFull));
    out[tid*Tz + Tz-1] = tk;
  }
}

extern "C" void kernel_launch(void* const* d_in, const int* in_sizes, int n_in,
                              void* d_out, int out_size, void* d_ws, size_t ws_size,
                              hipStream_t stream) {
  const int*   input_x   = (const int*)d_in[0];
  const int*   gnp       = (const int*)d_in[1];
  const int*   start_tok = (const int*)d_in[2];
  const float* emb = (const float*)d_in[3];
  const float* Wi  = (const float*)d_in[4];
  const float* Ui  = (const float*)d_in[5];
  const float* bi  = (const float*)d_in[6];
  const float* Wf  = (const float*)d_in[7];
  const float* Uf  = (const float*)d_in[8];
  const float* bff = (const float*)d_in[9];
  const float* Wog = (const float*)d_in[10];
  const float* Uog = (const float*)d_in[11];
  const float* bog = (const float*)d_in[12];
  const float* Wc  = (const float*)d_in[13];
  const float* Uc  = (const float*)d_in[14];
  const float* bc  = (const float*)d_in[15];
  const float* Wo  = (const float*)d_in[16];
  const float* bo  = (const float*)d_in[17];
  int* out = (int*)d_out;

  float* wsf = (float*)d_ws;
  float* hA  = wsf;                       // 16384 f
  float* hB  = wsf + 16384;               // 16384 f
  float* c_g = wsf + 32768;               // 16384 f
  float* hT  = wsf + 49152;               // 16384 f
  u64*   key = (u64*)(wsf + 65536);       // 128 u64

  static int lds_set = 0;
  size_t lds_bytes = (size_t)LDS_FLOATS * 4;
  if (!lds_set) {
    hipFuncSetAttribute((const void*)k_rollout,
                        hipFuncAttributeMaxDynamicSharedMemorySize, (int)lds_bytes);
    lds_set = 1;
  }

  void* args[] = {
    (void*)&input_x, (void*)&gnp, (void*)&start_tok, (void*)&emb,
    (void*)&Wi, (void*)&Ui, (void*)&bi,
    (void*)&Wf, (void*)&Uf, (void*)&bff,
    (void*)&Wog, (void*)&Uog, (void*)&bog,
    (void*)&Wc, (void*)&Uc, (void*)&bc,
    (void*)&Wo, (void*)&bo,
    (void*)&hA, (void*)&hB, (void*)&c_g, (void*)&hT, (void*)&key, (void*)&out
  };
  hipLaunchCooperativeKernel((void*)k_rollout, dim3(NBLK), dim3(1024),
                             args, (unsigned)lds_bytes, stream);
}

// Round 4
// 1102.144 us; speedup vs baseline: 2.6312x; 2.6312x over previous
//
#include <hip/hip_runtime.h>
#include <math.h>
#include <stdint.h>

#define Bz 64
#define Tz 32
#define Ez 64
#define Hz 256
#define Vz 32000
#define KTOT 320
#define CQ  8000      // Vz/4 float4s per Wo row

typedef unsigned long long u64;
typedef unsigned int u32;

__device__ __forceinline__ u32 map_f32(float f) {
  u32 u = __float_as_uint(f);
  return (u & 0x80000000u) ? ~u : (u | 0x80000000u);
}

// ---------------- weight repack: P2[j][g][k] contiguous k-runs; zero key bufs -----------
__global__ void k_prep(const float* __restrict__ Wi, const float* __restrict__ Ui,
                       const float* __restrict__ Wf, const float* __restrict__ Uf,
                       const float* __restrict__ Wog, const float* __restrict__ Uog,
                       const float* __restrict__ Wc, const float* __restrict__ Uc,
                       float* __restrict__ P2, u64* __restrict__ key) {
  int j = blockIdx.x;        // 0..255
  int k = threadIdx.x;       // 0..319
  float g0, g1, g2, g3;
  if (k < Ez) {
    g0 = Wi[k*Hz + j]; g1 = Wf[k*Hz + j]; g2 = Wog[k*Hz + j]; g3 = Wc[k*Hz + j];
  } else {
    int kk = k - Ez;
    g0 = Ui[kk*Hz + j]; g1 = Uf[kk*Hz + j]; g2 = Uog[kk*Hz + j]; g3 = Uc[kk*Hz + j];
  }
  P2[(size_t)(j*4 + 0)*KTOT + k] = g0;
  P2[(size_t)(j*4 + 1)*KTOT + k] = g1;
  P2[(size_t)(j*4 + 2)*KTOT + k] = g2;
  P2[(size_t)(j*4 + 3)*KTOT + k] = g3;
  if (j == 0 && k < 2*Bz) key[k] = 0ull;   // both parity buffers
}

// ---------------- per-step LSTM cell: 256 blocks (one j each) x 256 thr (64b x 4 gates) --
__global__ __launch_bounds__(256) void k_gates(
    int t, const int* __restrict__ gnp,
    const int* __restrict__ input_x, const int* __restrict__ start_tok,
    const float* __restrict__ emb, const float* __restrict__ P2,
    const float* __restrict__ bi_, const float* __restrict__ bf_,
    const float* __restrict__ bog_, const float* __restrict__ bc_,
    const float* __restrict__ h_in, float* __restrict__ h_out,
    float* __restrict__ c_g,
    const u64* __restrict__ key_prev, u64* __restrict__ key_cur,
    int* __restrict__ out) {
  __shared__ int tok_s[Bz];
  int tid = threadIdx.x;
  int j = blockIdx.x;          // 0..255
  int b = tid >> 2, q = tid & 3;
  int gn = *gnp;

  // ---- token pick for step t ----
  if (q == 0) {
    int tk;
    if (t == 0) tk = start_tok[b];
    else if (t - 1 < gn) tk = input_x[b*Tz + (t - 1)];
    else tk = (int)(~(u32)(key_prev[b] & 0xFFFFFFFFull));
    tok_s[b] = tk;
    if (j == 0 && t > 0) out[b*Tz + (t - 1)] = tk;
  }
  if (j == 0 && q == 1) key_cur[b] = 0ull;   // reset for this step's k_logits
  __syncthreads();

  // ---- one gate dot per thread: gate q of (b, j), K = 64 emb + 256 h ----
  const float* wrow = P2 + (size_t)(j*4 + q)*KTOT;
  const float* xrow = emb + (size_t)tok_s[b]*Ez;
  float a = 0.f;
  #pragma unroll
  for (int k = 0; k < Ez; k += 4) {
    float4 xv = *(const float4*)(xrow + k);
    float4 wv = *(const float4*)(wrow + k);
    a = fmaf(xv.x, wv.x, a); a = fmaf(xv.y, wv.y, a);
    a = fmaf(xv.z, wv.z, a); a = fmaf(xv.w, wv.w, a);
  }
  if (t > 0) {
    const float* hrow = h_in + b*Hz;
    #pragma unroll 8
    for (int k = 0; k < Hz; k += 4) {
      float4 xv = *(const float4*)(hrow + k);
      float4 wv = *(const float4*)(wrow + Ez + k);
      a = fmaf(xv.x, wv.x, a); a = fmaf(xv.y, wv.y, a);
      a = fmaf(xv.z, wv.z, a); a = fmaf(xv.w, wv.w, a);
    }
  }
  a += (q == 0) ? bi_[j] : (q == 1) ? bf_[j] : (q == 2) ? bog_[j] : bc_[j];

  // ---- gather the 4 gate pre-activations across the 4-lane group ----
  int lane = tid & 63;
  int base = lane & ~3;
  float ai = __shfl(a, base + 0, 64);
  float af = __shfl(a, base + 1, 64);
  float ao = __shfl(a, base + 2, 64);
  float ac = __shfl(a, base + 3, 64);
  float gi = 1.f / (1.f + expf(-ai));
  float gf = 1.f / (1.f + expf(-af));
  float go = 1.f / (1.f + expf(-ao));
  float gc = tanhf(ac);
  float cold = (t > 0) ? c_g[b*Hz + j] : 0.f;
  float cn = gf*cold + gi*gc;
  float hn = go * tanhf(cn);
  if (q == 0)      h_out[b*Hz + j] = hn;
  else if (q == 1) c_g[b*Hz + j]   = cn;
}

// ---------------- logits: 512 blocks x 256 thr; block = 32 rows x 128 cols ---------------
// XCD-pair swizzle: blocks id and id^8 share a Wo col-tile and land on the same XCD.
__global__ __launch_bounds__(256, 2) void k_logits(
    int t, const int* __restrict__ gnp,
    const float* __restrict__ h_g,       // row-major [64][256], = h_out of this step
    const float* __restrict__ Wo, const float* __restrict__ bo,
    u64* __restrict__ key_cur) {
  int gn = *gnp;
  if (t < gn) return;                    // teacher step
  int id = blockIdx.x;
  int p    = (id & 7) | ((id >> 4) << 3);  // col-tile 0..255
  int half = (id >> 3) & 1;                // row half
  if (p >= 250) return;

  __shared__ float hLDS[32*256];         // 32 KB
  int tid = threadIdx.x;
  int rbase = half * 32;

  // stage h rows rbase..rbase+31 (coalesced float4, conflict-free linear writes)
  {
    const float4* h4 = (const float4*)(h_g + rbase*Hz);
    float4* hl4 = (float4*)hLDS;
    #pragma unroll
    for (int i = 0; i < 8; ++i) hl4[tid + i*256] = h4[tid + i*256];
  }
  __syncthreads();

  int rg = tid >> 5;           // 0..7 -> rows rbase + rg*4 (2 rgroups per wave: 2-way LDS, free)
  int cg = tid & 31;           // cols c0 = p*128 + cg*4
  int r0 = rg * 4;
  int c0 = p*128 + cg*4;

  float acc[4][4];
  {
    float4 b4 = *(const float4*)(bo + c0);
    #pragma unroll
    for (int i = 0; i < 4; ++i) { acc[i][0]=b4.x; acc[i][1]=b4.y; acc[i][2]=b4.z; acc[i][3]=b4.w; }
  }

  const float4* Wp = ((const float4*)Wo) + (c0 >> 2);
  const float* hb0 = hLDS + (r0+0)*Hz;
  const float* hb1 = hLDS + (r0+1)*Hz;
  const float* hb2 = hLDS + (r0+2)*Hz;
  const float* hb3 = hLDS + (r0+3)*Hz;

  float4 Wa[4], Wb[4], Ha[4], Hb[4];

#define LDW(B, kk) { const float4* _w = Wp + (size_t)(kk)*CQ; \
    B[0] = _w[0]; B[1] = _w[CQ]; B[2] = _w[2*CQ]; B[3] = _w[3*CQ]; }
#define LDH(B, kk) { B[0] = *(const float4*)(hb0 + (kk)); B[1] = *(const float4*)(hb1 + (kk)); \
    B[2] = *(const float4*)(hb2 + (kk)); B[3] = *(const float4*)(hb3 + (kk)); }
#define DOFMA(HB, WB) { \
    _Pragma("unroll") \
    for (int kk = 0; kk < 4; ++kk) { \
      float4 w = WB[kk]; \
      _Pragma("unroll") \
      for (int i = 0; i < 4; ++i) { \
        float a = ((const float*)&HB[i])[kk]; \
        acc[i][0] = fmaf(a, w.x, acc[i][0]); acc[i][1] = fmaf(a, w.y, acc[i][1]); \
        acc[i][2] = fmaf(a, w.z, acc[i][2]); acc[i][3] = fmaf(a, w.w, acc[i][3]); } } }

  LDW(Wa, 0); LDH(Ha, 0);
  for (int k = 0; k < Hz - 8; k += 8) {
    LDW(Wb, k+4); LDH(Hb, k+4);
    DOFMA(Ha, Wa);
    LDW(Wa, k+8); LDH(Ha, k+8);
    DOFMA(Hb, Wb);
  }
  LDW(Wb, Hz-4); LDH(Hb, Hz-4);
  DOFMA(Ha, Wa);
  DOFMA(Hb, Wb);
#undef LDW
#undef LDH
#undef DOFMA

  // per-row argmax: 4 local cols, then half-wave (32 cgroups) shuffle reduce
  #pragma unroll
  for (int i = 0; i < 4; ++i) {
    float bv = acc[i][0]; int bix = c0;
    #pragma unroll
    for (int cc = 1; cc < 4; ++cc)
      if (acc[i][cc] > bv) { bv = acc[i][cc]; bix = c0 + cc; }
    for (int m = 16; m > 0; m >>= 1) {
      float ov = __shfl_xor(bv, m, 32);
      int   oi = __shfl_xor(bix, m, 32);
      if (ov > bv || (ov == bv && oi < bix)) { bv = ov; bix = oi; }
    }
    if (cg == 0) {
      u64 kv = ((u64)map_f32(bv) << 32) | (u32)(~(u32)bix);
      atomicMax(&key_cur[rbase + r0 + i], kv);
    }
  }
}

// ---------------- final token (step T-1) -------------------------------------------------
__global__ void k_final(const int* __restrict__ gnp, const int* __restrict__ input_x,
                        const u64* __restrict__ key_last, int* __restrict__ out) {
  int b = threadIdx.x;
  int gn = *gnp;
  int tk;
  if (Tz - 1 < gn) tk = input_x[b*Tz + Tz - 1];
  else             tk = (int)(~(u32)(key_last[b] & 0xFFFFFFFFull));
  out[b*Tz + Tz - 1] = tk;
}

extern "C" void kernel_launch(void* const* d_in, const int* in_sizes, int n_in,
                              void* d_out, int out_size, void* d_ws, size_t ws_size,
                              hipStream_t stream) {
  const int*   input_x   = (const int*)d_in[0];
  const int*   gnp       = (const int*)d_in[1];
  const int*   start_tok = (const int*)d_in[2];
  const float* emb = (const float*)d_in[3];
  const float* Wi  = (const float*)d_in[4];
  const float* Ui  = (const float*)d_in[5];
  const float* bi  = (const float*)d_in[6];
  const float* Wf  = (const float*)d_in[7];
  const float* Uf  = (const float*)d_in[8];
  const float* bff = (const float*)d_in[9];
  const float* Wog = (const float*)d_in[10];
  const float* Uog = (const float*)d_in[11];
  const float* bog = (const float*)d_in[12];
  const float* Wc  = (const float*)d_in[13];
  const float* Uc  = (const float*)d_in[14];
  const float* bc  = (const float*)d_in[15];
  const float* Wo  = (const float*)d_in[16];
  const float* bo  = (const float*)d_in[17];
  int* out = (int*)d_out;

  float* wsf = (float*)d_ws;
  float* hA  = wsf;                      // 16384 f
  float* hB  = wsf + 16384;              // 16384 f
  float* c_g = wsf + 32768;              // 16384 f
  u64*   key = (u64*)(wsf + 49152);      // 128 u64 = 256 f
  float* P2  = wsf + 49152 + 256;        // 327680 f

  k_prep<<<dim3(256), dim3(320), 0, stream>>>(Wi, Ui, Wf, Uf, Wog, Uog, Wc, Uc, P2, key);

  for (int t = 0; t < Tz; ++t) {
    const float* h_in  = (t & 1) ? hA : hB;
    float*       h_out = (t & 1) ? hB : hA;
    const u64* key_prev = key + ((t + 1) & 1) * Bz;
    u64*       key_cur  = key + (t & 1) * Bz;
    k_gates<<<dim3(256), dim3(256), 0, stream>>>(
        t, gnp, input_x, start_tok, emb, P2, bi, bff, bog, bc,
        h_in, h_out, c_g, key_prev, key_cur, out);
    k_logits<<<dim3(512), dim3(256), 0, stream>>>(
        t, gnp, h_out, Wo, bo, key_cur);
  }
  k_final<<<dim3(1), dim3(64), 0, stream>>>(
      gnp, input_x, key + ((Tz - 1) & 1) * Bz, out);
}